// Round 3
// baseline (1520.310 us; speedup 1.0000x reference)
//
#include <hip/hip_runtime.h>
#include <math.h>

// TopKGating: logits = x @ W^T + b  -> softmax(8) -> top-2 (indices, values)
// x: [131072, 1024] f32, W: [8, 1024] f32, b: [8] f32
// out: [N*2] indices (as float) then [N*2] values, flat concat.
//
// Round-2 post-mortem: register-prefetch pf[16] was scratch-spilled ->
// WRITE_SIZE == sizeof(x) (537 MB of scratch writeback) + latency chains.
// This version has NO x staging at all: W lives in LDS (makes the only
// non-uniform operand cheap), x goes global->VGPR->FMA with full-line
// coalescing (4 tokens x 256B contiguous segments per instruction), and
// per-token partial sums are combined with shfl_xor butterflies.
// Only persistent state: 64 acc VGPRs. Nothing to spill.

#define NUM_TOKENS 131072
#define DIM        1024
#define D4         (DIM / 4)     // 256 float4 per token
#define NE         8
#define TPB        256           // 4 waves per block
#define NBLK       512           // 2048 waves; 2 tiles per wave
#define TG         8             // token groups per tile (4 tokens each)
#define TILE_TOK   (TG * 4)      // 32 tokens per wave-tile
#define NTILES     (NUM_TOKENS / TILE_TOK)  // 4096

__global__ __launch_bounds__(TPB, 2)
void topk_gating_kernel(const float* __restrict__ x,
                        const float* __restrict__ W,
                        const float* __restrict__ b,
                        float* __restrict__ out)
{
    // W: [8][256] float4 = 32 KB, staged once per block.
    __shared__ float4 Wl[NE * D4];
    const float4* W4 = (const float4*)W;
    for (int i = threadIdx.x; i < NE * D4; i += TPB) Wl[i] = W4[i];
    __syncthreads();  // only barrier in the kernel

    const int wave = threadIdx.x >> 6;
    const int lane = threadIdx.x & 63;
    const int r    = lane >> 4;   // token within group-of-4
    const int lo   = lane & 15;   // float4 col within 256B segment
    const int gw   = blockIdx.x * 4 + wave;  // global wave id, 0..2047

    const float4* x4 = (const float4*)x;
    float2* outi = (float2*)out;                            // indices (as float)
    float2* outv = (float2*)(out + 2 * (size_t)NUM_TOKENS); // values

    for (int tile = gw; tile < NTILES; tile += NBLK * 4) {
        const int tok0 = tile * TILE_TOK;

        float acc[TG][NE];
#pragma unroll
        for (int g = 0; g < TG; ++g)
#pragma unroll
            for (int e = 0; e < NE; ++e) acc[g][e] = 0.f;

#pragma unroll
        for (int j = 0; j < 16; ++j) {
            // W fragment for this j: one LDS address VGPR + imm offsets; 256B
            // span across the 16 lo-lanes (2-way pattern -> conflict-free).
            float4 w[NE];
#pragma unroll
            for (int e = 0; e < NE; ++e) w[e] = Wl[e * D4 + j * 16 + lo];

#pragma unroll
            for (int g = 0; g < TG; ++g) {
                // 4 tokens x 256B contiguous segments per wave instruction.
                float4 xv = x4[(size_t)(tok0 + g * 4 + r) * D4 + j * 16 + lo];
#pragma unroll
                for (int e = 0; e < NE; ++e) {
                    acc[g][e] = fmaf(xv.x, w[e].x, acc[g][e]);
                    acc[g][e] = fmaf(xv.y, w[e].y, acc[g][e]);
                    acc[g][e] = fmaf(xv.z, w[e].z, acc[g][e]);
                    acc[g][e] = fmaf(xv.w, w[e].w, acc[g][e]);
                }
            }
        }

        // Reduce partials across the 16 lanes sharing each token, then
        // epilogue (redundant on all 16 lanes; only lo==0 stores).
#pragma unroll
        for (int g = 0; g < TG; ++g) {
            float logit[NE];
#pragma unroll
            for (int e = 0; e < NE; ++e) {
                float v = acc[g][e];
                v += __shfl_xor(v, 1);
                v += __shfl_xor(v, 2);
                v += __shfl_xor(v, 4);
                v += __shfl_xor(v, 8);
                logit[e] = v + b[e];
            }

            // stable top-2 (ties -> lower index, matches lax.top_k)
            float v1 = -INFINITY, v2 = -INFINITY;
            int   i1 = 0,         i2 = 0;
#pragma unroll
            for (int e = 0; e < NE; ++e) {
                float v = logit[e];
                if (v > v1)      { v2 = v1; i2 = i1; v1 = v; i1 = e; }
                else if (v > v2) { v2 = v;  i2 = e; }
            }
            float sum = 0.f;
#pragma unroll
            for (int e = 0; e < NE; ++e) sum += __expf(logit[e] - v1);
            float inv = 1.0f / sum;
            float p1  = inv;
            float p2  = __expf(v2 - v1) * inv;

            if (lo == 0) {
                int n = tok0 + g * 4 + r;
                outi[n] = make_float2((float)i1, (float)i2);
                outv[n] = make_float2(p1, p2);
            }
        }
    }
}

extern "C" void kernel_launch(void* const* d_in, const int* in_sizes, int n_in,
                              void* d_out, int out_size, void* d_ws, size_t ws_size,
                              hipStream_t stream) {
    const float* x = (const float*)d_in[0];
    const float* W = (const float*)d_in[1];
    const float* b = (const float*)d_in[2];
    float* out = (float*)d_out;

    topk_gating_kernel<<<dim3(NBLK), dim3(TPB), 0, stream>>>(x, W, b, out);
}